// Round 3
// baseline (194.683 us; speedup 1.0000x reference)
//
#include <hip/hip_runtime.h>
#include <math.h>

// ---------------------------------------------------------------------------
// ClusterML pipeline (round 3):
//   1) gemm:    out_bf16 = bf16(x @ W.T + b); rnorm = ||row||^2
//               LDS double-buffer + async-stage split (T14)
//   2) segsum:  wave-per-row conflict-free LDS atomics, 512 blocks
//   3) reduce:  256 blocks, 8-way j-sliced + LDS tree
//   4) centroid: 64 blocks (one per class)
//   5) dist:    blocks [0,1024): sigmoid(exp(-0.5*dist)); [1024,1040): proto
// ---------------------------------------------------------------------------

typedef __bf16 bf16;
typedef bf16  bf16x2 __attribute__((ext_vector_type(2)));
typedef bf16  bf16x4 __attribute__((ext_vector_type(4)));
typedef bf16  bf16x8 __attribute__((ext_vector_type(8)));
typedef float f32x4  __attribute__((ext_vector_type(4)));

#define B_ROWS 131072
#define K_DIM  512
#define E_DIM  128
#define C_CLS  64

#define BM 128
#define BK 64

#define SEG_BLOCKS 512
#define ROWS_PER_SEG (B_ROWS / SEG_BLOCKS)   // 256

#define DIST_BLOCKS (B_ROWS / 128)           // 1024
#define PROTO_BLOCKS 16

// -------------------- Kernel 1: gemm + rnorm (dbuf + T14) ------------------
__global__ __launch_bounds__(256, 2)
void gemm_kernel(const float* __restrict__ x, const float* __restrict__ W,
                 const float* __restrict__ bias, bf16* __restrict__ outb,
                 float* __restrict__ rnorm)
{
    __shared__ bf16 As[2][BM * BK];   // 2 x 16KB, XOR-swizzled rows
    __shared__ bf16 Bs[2][BM * BK];
    __shared__ float lr[BM];

    const int t    = threadIdx.x;
    const int lane = t & 63;
    const int w    = t >> 6;
    const int wr   = w >> 1;
    const int wc   = w & 1;
    const int fr   = lane & 15;
    const int fq   = lane >> 4;
    const long blockRow = (long)blockIdx.x * BM;

    const int srow = t >> 4;          // 0..15
    const int scol = (t & 15) * 4;    // 0..60

    f32x4 acc[4][4] = {};
    f32x4 va[8], vb[8];

    const float* xg = x + blockRow * K_DIM;
    if (t < BM) lr[t] = 0.f;

    // prologue: load tile 0 into regs, stage to buf 0
    #pragma unroll
    for (int r = 0; r < 8; ++r) {
        int row = r * 16 + srow;
        va[r] = *(const f32x4*)(xg + (long)row * K_DIM + scol);
        vb[r] = *(const f32x4*)(W  + (long)row * K_DIM + scol);
    }
    #pragma unroll
    for (int r = 0; r < 8; ++r) {
        int row = r * 16 + srow;
        bf16x4 pa = { (bf16)va[r].x, (bf16)va[r].y, (bf16)va[r].z, (bf16)va[r].w };
        bf16x4 pb = { (bf16)vb[r].x, (bf16)vb[r].y, (bf16)vb[r].z, (bf16)vb[r].w };
        int byte = row * (BK * 2) + ((scol * 2) ^ ((row & 7) << 4));
        *(bf16x4*)((char*)As[0] + byte) = pa;
        *(bf16x4*)((char*)Bs[0] + byte) = pb;
    }
    __syncthreads();

    for (int kti = 0; kti < K_DIM / BK; ++kti) {
        const int p = kti & 1;
        // T14: issue next tile's loads BEFORE compute
        if (kti < K_DIM / BK - 1) {
            const int kt = (kti + 1) * BK;
            #pragma unroll
            for (int r = 0; r < 8; ++r) {
                int row = r * 16 + srow;
                va[r] = *(const f32x4*)(xg + (long)row * K_DIM + kt + scol);
                vb[r] = *(const f32x4*)(W  + (long)row * K_DIM + kt + scol);
            }
        }
        // compute from buf p
        const bf16* Ap = As[p];
        const bf16* Bp = Bs[p];
        #pragma unroll
        for (int kk = 0; kk < 2; ++kk) {
            bf16x8 af[4], bg[4];
            #pragma unroll
            for (int m = 0; m < 4; ++m) {
                int row  = wr * 64 + m * 16 + fr;
                int byte = row * (BK * 2) + (((kk * 32 + fq * 8) * 2) ^ ((row & 7) << 4));
                af[m] = *(const bf16x8*)((const char*)Ap + byte);
            }
            #pragma unroll
            for (int n = 0; n < 4; ++n) {
                int row  = wc * 64 + n * 16 + fr;
                int byte = row * (BK * 2) + (((kk * 32 + fq * 8) * 2) ^ ((row & 7) << 4));
                bg[n] = *(const bf16x8*)((const char*)Bp + byte);
            }
            #pragma unroll
            for (int m = 0; m < 4; ++m)
                #pragma unroll
                for (int n = 0; n < 4; ++n)
                    acc[m][n] = __builtin_amdgcn_mfma_f32_16x16x32_bf16(
                        af[m], bg[n], acc[m][n], 0, 0, 0);
        }
        // write-late: convert + stage into buf p^1, one barrier per iter
        if (kti < K_DIM / BK - 1) {
            #pragma unroll
            for (int r = 0; r < 8; ++r) {
                int row = r * 16 + srow;
                bf16x4 pa = { (bf16)va[r].x, (bf16)va[r].y, (bf16)va[r].z, (bf16)va[r].w };
                bf16x4 pb = { (bf16)vb[r].x, (bf16)vb[r].y, (bf16)vb[r].z, (bf16)vb[r].w };
                int byte = row * (BK * 2) + ((scol * 2) ^ ((row & 7) << 4));
                *(bf16x4*)((char*)As[p ^ 1] + byte) = pa;
                *(bf16x4*)((char*)Bs[p ^ 1] + byte) = pb;
            }
            __syncthreads();
        }
    }

    // epilogue: C/D layout col = lane&15, row = (lane>>4)*4 + j
    float bvv[4];
    #pragma unroll
    for (int n = 0; n < 4; ++n) bvv[n] = bias[wc * 64 + n * 16 + fr];

    #pragma unroll
    for (int m = 0; m < 4; ++m) {
        #pragma unroll
        for (int j = 0; j < 4; ++j) {
            long grow = blockRow + wr * 64 + m * 16 + fq * 4 + j;
            float s = 0.f;
            #pragma unroll
            for (int n = 0; n < 4; ++n) {
                float v = acc[m][n][j] + bvv[n];
                outb[grow * E_DIM + wc * 64 + n * 16 + fr] = (bf16)v;
                s += v * v;
            }
            s += __shfl_xor(s, 1); s += __shfl_xor(s, 2);
            s += __shfl_xor(s, 4); s += __shfl_xor(s, 8);
            if (fr == 0) atomicAdd(&lr[wr * 64 + m * 16 + fq * 4 + j], s);
        }
    }
    __syncthreads();
    if (t < BM) rnorm[blockRow + t] = lr[t];
}

// -------------------- Kernel 2: per-class partial sums ---------------------
// wave-per-row: 64 lanes x 2 cols -> atomic addrs lane-consecutive (2-way, free)
__global__ __launch_bounds__(256)
void segsum_kernel(const bf16* __restrict__ outb, const int* __restrict__ y,
                   float* __restrict__ pw, float* __restrict__ pc)
{
    __shared__ float lsum[C_CLS * E_DIM];
    __shared__ float lcnt[C_CLS];
    __shared__ int   ly[ROWS_PER_SEG];
    const int t = threadIdx.x;
    for (int i = t; i < C_CLS * E_DIM; i += 256) lsum[i] = 0.f;
    if (t < C_CLS) lcnt[t] = 0.f;
    const long base = (long)blockIdx.x * ROWS_PER_SEG;
    if (t < ROWS_PER_SEG) ly[t] = y[base + t];
    __syncthreads();
    const int w = t >> 6, lane = t & 63;
    #pragma unroll 4
    for (int i = w; i < ROWS_PER_SEG; i += 4) {
        int cls = ly[i];
        bf16x2 v = *(const bf16x2*)(outb + (base + i) * E_DIM + lane * 2);
        atomicAdd(&lsum[cls * E_DIM + lane * 2 + 0], (float)v[0]);
        atomicAdd(&lsum[cls * E_DIM + lane * 2 + 1], (float)v[1]);
        if (lane == 0) atomicAdd(&lcnt[cls], 1.f);
    }
    __syncthreads();
    for (int i = t; i < C_CLS * E_DIM; i += 256)
        pw[(long)blockIdx.x * (C_CLS * E_DIM) + i] = lsum[i];
    if (t < C_CLS) pc[blockIdx.x * C_CLS + t] = lcnt[t];
}

// -------------------- Kernel 3: reduce partials (256 blocks) ---------------
__global__ __launch_bounds__(256)
void reduce_kernel(const float* __restrict__ pw, float* __restrict__ sums)
{
    __shared__ float red[256];
    const int t = threadIdx.x;
    const int idx = blockIdx.x * 32 + (t & 31);
    const int js  = t >> 5;                     // 8 slices x 64 j's
    float s = 0.f;
    #pragma unroll 8
    for (int j = js * 64; j < js * 64 + 64; ++j)
        s += pw[(long)j * (C_CLS * E_DIM) + idx];
    red[t] = s;
    __syncthreads();
    if (t < 32) {
        float r = red[t];
        #pragma unroll
        for (int k = 1; k < 8; ++k) r += red[t + 32 * k];
        sums[blockIdx.x * 32 + t] = r;
    }
}

// -------------------- Kernel 4: centroids + norms (64 blocks) --------------
__global__ __launch_bounds__(256)
void centroid_kernel(const float* __restrict__ sums, const float* __restrict__ pc,
                     const float* __restrict__ centroid0,
                     float* __restrict__ cent, float* __restrict__ cnorm)
{
    __shared__ float red[256];
    const int c = blockIdx.x;
    const int t = threadIdx.x;
    // count for class c: 512 partials
    float s = pc[t * C_CLS + c] + pc[(t + 256) * C_CLS + c];
    red[t] = s;
    __syncthreads();
    #pragma unroll
    for (int st = 128; st > 0; st >>= 1) {
        if (t < st) red[t] += red[t + st];
        __syncthreads();
    }
    const float cnt = red[0];
    __syncthreads();
    float v = 0.f;
    if (t < E_DIM) {
        v = centroid0[c * E_DIM + t] + sums[c * E_DIM + t] / cnt;
        cent[c * E_DIM + t] = v;
    }
    red[t] = v * v;
    __syncthreads();
    #pragma unroll
    for (int st = 64; st > 0; st >>= 1) {
        if (t < st) red[t] += red[t + st];
        __syncthreads();
    }
    if (t == 0) cnorm[c] = red[0];
}

// -------------------- Kernel 5: dist + sigmoid (+ fused proto) -------------
__global__ __launch_bounds__(256, 4)
void dist_kernel(const bf16* __restrict__ outb, const float* __restrict__ cent,
                 const float* __restrict__ cnorm, const float* __restrict__ rnorm,
                 float* __restrict__ out0, float* __restrict__ proto)
{
    __shared__ float smemf[C_CLS * 129 + C_CLS + 128];
    const int t = threadIdx.x;

    if (blockIdx.x >= DIST_BLOCKS) {
        float* scf   = smemf;                    // [64][129]
        float* pnorm = smemf + C_CLS * 129;
        for (int idx = t; idx < C_CLS * E_DIM; idx += 256)
            scf[(idx >> 7) * 129 + (idx & 127)] = cent[idx];
        if (t < C_CLS) pnorm[t] = cnorm[t];
        __syncthreads();
        int p = (blockIdx.x - DIST_BLOCKS) * 256 + t;
        int i = p >> 6, j = p & 63;
        float d = 0.f;
        #pragma unroll 4
        for (int e = 0; e < E_DIM; ++e)
            d += scf[i * 129 + e] * scf[j * 129 + e];
        float d2 = pnorm[i] + pnorm[j] - 2.f * d;
        proto[p] = __expf(-0.5f * sqrtf(fmaxf(d2, 1e-12f)));
        return;
    }

    bf16*  Cs     = (bf16*)smemf;                // [64][128] bf16, swizzled
    float* snorm  = smemf + C_CLS * 129;
    float* srnorm = snorm + C_CLS;
    {
        int srw = t >> 5;
        int scl = (t & 31) * 4;
        #pragma unroll
        for (int r = 0; r < 8; ++r) {
            int row = r * 8 + srw;
            f32x4 v = *(const f32x4*)(cent + row * E_DIM + scl);
            bf16x4 pv = { (bf16)v.x, (bf16)v.y, (bf16)v.z, (bf16)v.w };
            int byte = row * (E_DIM * 2) + ((scl * 2) ^ ((row & 7) << 4));
            *(bf16x4*)((char*)Cs + byte) = pv;
        }
        if (t < C_CLS) snorm[t] = cnorm[t];
        if (t < 32) ((f32x4*)srnorm)[t] =
            ((const f32x4*)(rnorm + (long)blockIdx.x * 128))[t];
    }
    const int lane = t & 63;
    const int w    = t >> 6;
    const int fr   = lane & 15;
    const int fq   = lane >> 4;
    const long blkrow = (long)blockIdx.x * 128;
    f32x4 acc[2][4] = {};
    __syncthreads();
    #pragma unroll
    for (int kt = 0; kt < 4; ++kt) {
        bf16x8 af[2];
        #pragma unroll
        for (int m = 0; m < 2; ++m) {
            long row = blkrow + w * 32 + m * 16 + fr;
            af[m] = *(const bf16x8*)(outb + row * E_DIM + kt * 32 + fq * 8);
        }
        #pragma unroll
        for (int n = 0; n < 4; ++n) {
            int row  = n * 16 + fr;
            int byte = row * (E_DIM * 2) + (((kt * 32 + fq * 8) * 2) ^ ((row & 7) << 4));
            bf16x8 bq = *(const bf16x8*)((const char*)Cs + byte);
            acc[0][n] = __builtin_amdgcn_mfma_f32_16x16x32_bf16(af[0], bq, acc[0][n], 0, 0, 0);
            acc[1][n] = __builtin_amdgcn_mfma_f32_16x16x32_bf16(af[1], bq, acc[1][n], 0, 0, 0);
        }
    }
    #pragma unroll
    for (int m = 0; m < 2; ++m) {
        #pragma unroll
        for (int n = 0; n < 4; ++n) {
            int gcol = n * 16 + fr;
            float cn = snorm[gcol];
            #pragma unroll
            for (int j = 0; j < 4; ++j) {
                int lrow = w * 32 + m * 16 + fq * 4 + j;
                float d2 = srnorm[lrow] + cn - 2.f * acc[m][n][j];
                float dist = sqrtf(fmaxf(d2, 1e-12f));
                float ez = __expf(-0.5f * dist);
                out0[(blkrow + lrow) * C_CLS + gcol] = 1.f / (1.f + __expf(-ez));
            }
        }
    }
}

// ---------------------------------------------------------------------------
extern "C" void kernel_launch(void* const* d_in, const int* in_sizes, int n_in,
                              void* d_out, int out_size, void* d_ws, size_t ws_size,
                              hipStream_t stream)
{
    const float* x         = (const float*)d_in[0];
    const int*   y         = (const int*)d_in[1];
    const float* W         = (const float*)d_in[2];
    const float* bias      = (const float*)d_in[3];
    const float* centroid0 = (const float*)d_in[4];

    bf16*  outb  = (bf16*)d_ws;                                // 131072*128 bf16
    float* rnorm = (float*)((char*)d_ws + (size_t)B_ROWS * E_DIM * 2);
    float* pw    = rnorm + B_ROWS;                             // 512*8192
    float* pc    = pw + (long)SEG_BLOCKS * C_CLS * E_DIM;      // 512*64
    float* sums  = pc + SEG_BLOCKS * C_CLS;                    // 8192
    float* cent  = sums + C_CLS * E_DIM;                       // 8192
    float* cnorm = cent + C_CLS * E_DIM;                       // 64

    float* out0  = (float*)d_out;
    float* proto = out0 + (long)B_ROWS * C_CLS;

    gemm_kernel    <<<B_ROWS / BM, 256, 0, stream>>>(x, W, bias, outb, rnorm);
    segsum_kernel  <<<SEG_BLOCKS, 256, 0, stream>>>(outb, y, pw, pc);
    reduce_kernel  <<<(C_CLS * E_DIM) / 32, 256, 0, stream>>>(pw, sums);
    centroid_kernel<<<C_CLS, 256, 0, stream>>>(sums, pc, centroid0, cent, cnorm);
    dist_kernel    <<<DIST_BLOCKS + PROTO_BLOCKS, 256, 0, stream>>>(
        outb, cent, cnorm, rnorm, out0, proto);
}